// Round 1
// 283.334 us; speedup vs baseline: 1.7809x; 1.7809x over previous
//
#include <hip/hip_runtime.h>
#include <math.h>

#define D     2048
#define NR    32
#define ROWS  8
#define JP    68            // 64 payload dwords + 4 pad -> conflict-free b128 across jo
#define XRW   (32 * JP)     // 2176 dwords per row in LDS

__device__ __forceinline__ void fma4(float a, const float4& w, float4& o) {
    o.x = fmaf(a, w.x, o.x);
    o.y = fmaf(a, w.y, o.y);
    o.z = fmaf(a, w.z, o.z);
    o.w = fmaf(a, w.w, o.w);
}

__device__ __forceinline__ float wred(float v) {
    #pragma unroll
    for (int off = 32; off >= 1; off >>= 1) v += __shfl_xor(v, off);
    return v;
}

// ---------------- prep: wdp = gamma (.) wd ; c1 = colsum(wdp) ; c2 = colsum(beta (.) wd) ----
// grid 8 x 256 threads, one thread per j-row of wd. Partial c-sums per block -> c12p[blk][64].
__global__ __launch_bounds__(256)
void k_prep(const float* __restrict__ wd, const float* __restrict__ gamma,
            const float* __restrict__ beta, float* __restrict__ wdp,
            float* __restrict__ c12p)
{
    __shared__ float red[4][64];
    const int tid = threadIdx.x;
    const int l = tid & 63, w = tid >> 6;
    const int j = blockIdx.x * 256 + tid;

    const float gv = gamma[j], bv = beta[j];
    float4 c1a[8], c2a[8];
    #pragma unroll
    for (int q = 0; q < 8; ++q) {
        float4 wv = *(const float4*)(wd + j * NR + q * 4);
        float4 wp = make_float4(gv * wv.x, gv * wv.y, gv * wv.z, gv * wv.w);
        *(float4*)(wdp + j * NR + q * 4) = wp;
        c1a[q] = wp;
        c2a[q] = make_float4(bv * wv.x, bv * wv.y, bv * wv.z, bv * wv.w);
    }
    #pragma unroll
    for (int q = 0; q < 8; ++q) {
        c1a[q].x = wred(c1a[q].x); c1a[q].y = wred(c1a[q].y);
        c1a[q].z = wred(c1a[q].z); c1a[q].w = wred(c1a[q].w);
        c2a[q].x = wred(c2a[q].x); c2a[q].y = wred(c2a[q].y);
        c2a[q].z = wred(c2a[q].z); c2a[q].w = wred(c2a[q].w);
    }
    if (l == 0) {
        #pragma unroll
        for (int q = 0; q < 8; ++q) {
            red[w][q * 4 + 0] = c1a[q].x; red[w][q * 4 + 1] = c1a[q].y;
            red[w][q * 4 + 2] = c1a[q].z; red[w][q * 4 + 3] = c1a[q].w;
            red[w][32 + q * 4 + 0] = c2a[q].x; red[w][32 + q * 4 + 1] = c2a[q].y;
            red[w][32 + q * 4 + 2] = c2a[q].z; red[w][32 + q * 4 + 3] = c2a[q].w;
        }
    }
    __syncthreads();
    if (tid < 64)
        c12p[blockIdx.x * 64 + tid] = red[0][tid] + red[1][tid] + red[2][tid] + red[3][tid];
}

// ---------------- fused: LN-folded down-proj + GELU + up-proj + residual, 8 rows/block ----
__global__ __launch_bounds__(256, 2)
void k_fused(const float* __restrict__ x, const float* __restrict__ bd,
             const float* __restrict__ wu, const float* __restrict__ bu,
             const float* __restrict__ wdp, const float* __restrict__ c12p,
             float* __restrict__ out)
{
    __shared__ float xs[ROWS * XRW];        // 69632 B, raw x, padded chunk layout
    __shared__ float S4[4][ROWS][NR];       // per-wave down-proj partials
    __shared__ float a_s[ROWS][NR];         // gelu activations
    __shared__ float mu_s[ROWS], rs_s[ROWS];
    __shared__ float c1s[NR], c2s[NR], bds[NR];

    const int tid = threadIdx.x;
    const int w = tid >> 6, l = tid & 63;
    const long row0 = (long)blockIdx.x * ROWS;

    if (tid < NR) {
        float a1 = 0.f, a2 = 0.f;
        #pragma unroll
        for (int p = 0; p < 8; ++p) {
            a1 += c12p[p * 64 + tid];
            a2 += c12p[p * 64 + 32 + tid];
        }
        c1s[tid] = a1; c2s[tid] = a2; bds[tid] = bd[tid];
    }

    // ---- Phase A: stream x -> LDS (once), row stats ----
    #pragma unroll
    for (int rp = 0; rp < 2; ++rp) {
        const int row = w * 2 + rp;
        const float* xr = x + (row0 + row) * D;
        float s = 0.f, s2 = 0.f;
        #pragma unroll
        for (int it = 0; it < 8; ++it) {
            const int j = it * 256 + l * 4;
            float4 v = *(const float4*)(xr + j);
            *(float4*)&xs[row * XRW + (j >> 6) * JP + (j & 63)] = v;
            s  += v.x + v.y + v.z + v.w;
            s2 += v.x * v.x + v.y * v.y + v.z * v.z + v.w * v.w;
        }
        #pragma unroll
        for (int off = 32; off >= 1; off >>= 1) {
            s  += __shfl_xor(s, off);
            s2 += __shfl_xor(s2, off);
        }
        if (l == 0) {
            const float mu  = s * (1.0f / D);
            const float var = s2 * (1.0f / D) - mu * mu;
            mu_s[row] = mu;
            rs_s[row] = rsqrtf(var + 1e-5f);
        }
    }
    __syncthreads();

    // ---- Phase B: S[row][r] = sum_j x[row][j] * wdp[j][r]  (raw x; LN folded out) ----
    {
        const int rg = tid & 7, r0 = rg * 4, jo = tid >> 3;   // jo in 0..31, 64 j's each
        float4 acc[ROWS];
        #pragma unroll
        for (int m = 0; m < ROWS; ++m) acc[m] = make_float4(0.f, 0.f, 0.f, 0.f);

        const float* wp_base = wdp + (jo * 64) * NR + r0;
        #pragma unroll 4
        for (int tq = 0; tq < 16; ++tq) {
            const float4 w0 = *(const float4*)(wp_base + (tq * 4 + 0) * NR);
            const float4 w1 = *(const float4*)(wp_base + (tq * 4 + 1) * NR);
            const float4 w2 = *(const float4*)(wp_base + (tq * 4 + 2) * NR);
            const float4 w3 = *(const float4*)(wp_base + (tq * 4 + 3) * NR);
            #pragma unroll
            for (int m = 0; m < ROWS; ++m) {
                const float4 xv = *(const float4*)&xs[m * XRW + jo * JP + tq * 4];
                fma4(xv.x, w0, acc[m]);
                fma4(xv.y, w1, acc[m]);
                fma4(xv.z, w2, acc[m]);
                fma4(xv.w, w3, acc[m]);
            }
        }
        // reduce over the 8 jo-shards inside this wave (lane bits 3..5)
        #pragma unroll
        for (int m = 0; m < ROWS; ++m) {
            #pragma unroll
            for (int off = 8; off <= 32; off <<= 1) {
                acc[m].x += __shfl_xor(acc[m].x, off);
                acc[m].y += __shfl_xor(acc[m].y, off);
                acc[m].z += __shfl_xor(acc[m].z, off);
                acc[m].w += __shfl_xor(acc[m].w, off);
            }
        }
        if (l < 8) {
            #pragma unroll
            for (int m = 0; m < ROWS; ++m)
                *(float4*)&S4[w][m][l * 4] = acc[m];
        }
    }
    __syncthreads();

    // ---- GELU: y = rstd*(S - mu*c1) + c2 + bd ; a = gelu(y) ----
    {
        const int m = tid >> 5, r = tid & 31;   // 256 threads == 8 rows x 32 r
        const float S = S4[0][m][r] + S4[1][m][r] + S4[2][m][r] + S4[3][m][r];
        const float y = rs_s[m] * (S - mu_s[m] * c1s[r]) + c2s[r] + bds[r];
        a_s[m][r] = 0.5f * y * (1.0f + erff(y * 0.70710678118654752f));
    }
    __syncthreads();

    // ---- Phase C: out[row][j] = x[row][j] + bu[j] + sum_r a[row][r] * wu[r][j] ----
    #pragma unroll 1
    for (int c = 0; c < 2; ++c) {
        const int j  = c * 1024 + tid * 4;
        const int xo = (j >> 6) * JP + (j & 63);
        const float4 bv = *(const float4*)(bu + j);
        float4 o[ROWS];
        #pragma unroll
        for (int m = 0; m < ROWS; ++m) {
            const float4 xv = *(const float4*)&xs[m * XRW + xo];
            o[m] = make_float4(xv.x + bv.x, xv.y + bv.y, xv.z + bv.z, xv.w + bv.w);
        }
        #pragma unroll 4
        for (int rq = 0; rq < 8; ++rq) {
            float4 ar[ROWS];
            #pragma unroll
            for (int m = 0; m < ROWS; ++m)
                ar[m] = *(const float4*)&a_s[m][rq * 4];   // block-uniform broadcast
            #pragma unroll
            for (int rr = 0; rr < 4; ++rr) {
                const float4 wv = *(const float4*)(wu + (rq * 4 + rr) * D + j);
                #pragma unroll
                for (int m = 0; m < ROWS; ++m) {
                    const float av = (rr == 0) ? ar[m].x : (rr == 1) ? ar[m].y
                                   : (rr == 2) ? ar[m].z : ar[m].w;
                    fma4(av, wv, o[m]);
                }
            }
        }
        #pragma unroll
        for (int m = 0; m < ROWS; ++m) {
            float* op = out + (row0 + m) * D + j;
            __builtin_nontemporal_store(o[m].x, op + 0);
            __builtin_nontemporal_store(o[m].y, op + 1);
            __builtin_nontemporal_store(o[m].z, op + 2);
            __builtin_nontemporal_store(o[m].w, op + 3);
        }
    }
}

extern "C" void kernel_launch(void* const* d_in, const int* in_sizes, int n_in,
                              void* d_out, int out_size, void* d_ws, size_t ws_size,
                              hipStream_t stream) {
    (void)n_in; (void)ws_size; (void)out_size;
    const float* x     = (const float*)d_in[0];
    const float* gamma = (const float*)d_in[1];
    const float* beta  = (const float*)d_in[2];
    const float* wd    = (const float*)d_in[3];
    const float* bd    = (const float*)d_in[4];
    const float* wu    = (const float*)d_in[5];
    const float* bu    = (const float*)d_in[6];
    float* out  = (float*)d_out;
    float* wdp  = (float*)d_ws;          // 2048*32 fp32 = 256 KB
    float* c12p = wdp + D * NR;          // 8 blocks * 64 partials

    const int nrows  = in_sizes[0] / D;  // 16384
    const int blocks = nrows / ROWS;     // 2048

    hipLaunchKernelGGL(k_prep,  dim3(8),      dim3(256), 0, stream, wd, gamma, beta, wdp, c12p);
    hipLaunchKernelGGL(k_fused, dim3(blocks), dim3(256), 0, stream, x, bd, wu, bu, wdp, c12p, out);
}